// Round 3
// baseline (292.507 us; speedup 1.0000x reference)
//
#include <hip/hip_runtime.h>
#include <math.h>

// Mean over B rows of KL divergence between diagonal Gaussians.
// B=65536, N=256. out = 0.5 * (sum_all(term)/B - N), where
// term = log(s2)-log(s1) + s1/s2 + (mask*(mu2-mu1))^2/s2.
//
// R1/R2 post-mortem: latency-bound at 115us; compiler re-clusters loads
// into [5 loads -> vmcnt wait -> compute] groups (VGPR 20->36 only),
// leaving ~2KB/CU in flight. R3: force-hoist ALL of a thread's loads
// before any use, __launch_bounds__(256,4) to allow ~128 VGPRs, so each
// wave has 20 x 1KB loads in flight.

constexpr int B_ROWS = 65536;
constexpr int N_COLS = 256;
constexpr int TOTAL4 = (B_ROWS * N_COLS) / 4;  // 4,194,304 float4s per array
constexpr int GRID1  = 4096;
constexpr int BLOCK  = 256;
constexpr int ITERS  = TOTAL4 / (GRID1 * BLOCK);  // = 4 float4s/thread/array

__device__ __forceinline__ float kl_term(float m1, float m2, float s1, float s2, float mk) {
    m1 = __builtin_isnan(m1) ? 0.0f : m1;      // nan_to_num(mu1)
    float d  = mk * (m2 - m1);
    float r2 = __builtin_amdgcn_rcpf(s2);      // tolerance is 2%; approx ok
    float lg = 0.69314718055994531f * (__log2f(s2) - __log2f(s1));
    return lg + (s1 + d * d) * r2;
}

__device__ __forceinline__ float kl4(float4 a, float4 b, float4 p, float4 q, float4 m) {
    return kl_term(a.x, b.x, p.x, q.x, m.x)
         + kl_term(a.y, b.y, p.y, q.y, m.y)
         + kl_term(a.z, b.z, p.z, q.z, m.z)
         + kl_term(a.w, b.w, p.w, q.w, m.w);
}

__global__ __launch_bounds__(BLOCK, 4) void kl_partial_kernel(
    const float4* __restrict__ mu1, const float4* __restrict__ mu2,
    const float4* __restrict__ s1,  const float4* __restrict__ s2,
    const float4* __restrict__ mask, float* __restrict__ partials)
{
    const int base = blockIdx.x * (BLOCK * ITERS) + threadIdx.x;

    // Stage 1: issue ALL 20 loads (320 B/thread) before any use.
    float4 A[ITERS], Bv[ITERS], P[ITERS], Q[ITERS], M[ITERS];
    #pragma unroll
    for (int k = 0; k < ITERS; ++k) A[k]  = mu1[base + k * BLOCK];
    #pragma unroll
    for (int k = 0; k < ITERS; ++k) Bv[k] = mu2[base + k * BLOCK];
    #pragma unroll
    for (int k = 0; k < ITERS; ++k) P[k]  = s1[base + k * BLOCK];
    #pragma unroll
    for (int k = 0; k < ITERS; ++k) Q[k]  = s2[base + k * BLOCK];
    #pragma unroll
    for (int k = 0; k < ITERS; ++k) M[k]  = mask[base + k * BLOCK];

    // Stage 2: compute (independent partials to keep the FMA chain short).
    float acc0 = 0.0f, acc1 = 0.0f;
    #pragma unroll
    for (int k = 0; k < ITERS; k += 2) {
        acc0 += kl4(A[k],     Bv[k],     P[k],     Q[k],     M[k]);
        acc1 += kl4(A[k + 1], Bv[k + 1], P[k + 1], Q[k + 1], M[k + 1]);
    }
    float acc = acc0 + acc1;

    // wave-64 reduction
    #pragma unroll
    for (int off = 32; off > 0; off >>= 1) acc += __shfl_down(acc, off, 64);
    __shared__ float wsum[BLOCK / 64];
    const int lane = threadIdx.x & 63;
    const int wv   = threadIdx.x >> 6;
    if (lane == 0) wsum[wv] = acc;
    __syncthreads();
    if (threadIdx.x == 0) {
        float s = 0.0f;
        #pragma unroll
        for (int w = 0; w < BLOCK / 64; ++w) s += wsum[w];
        partials[blockIdx.x] = s;  // unconditional write every launch (poison-safe)
    }
}

__global__ __launch_bounds__(BLOCK) void kl_final_kernel(
    const float* __restrict__ partials, float* __restrict__ out)
{
    double acc = 0.0;
    for (int i = threadIdx.x; i < GRID1; i += BLOCK) acc += (double)partials[i];
    #pragma unroll
    for (int off = 32; off > 0; off >>= 1) acc += __shfl_down(acc, off, 64);
    __shared__ double wsum[BLOCK / 64];
    const int lane = threadIdx.x & 63;
    const int wv   = threadIdx.x >> 6;
    if (lane == 0) wsum[wv] = acc;
    __syncthreads();
    if (threadIdx.x == 0) {
        double s = 0.0;
        #pragma unroll
        for (int w = 0; w < BLOCK / 64; ++w) s += wsum[w];
        out[0] = (float)(0.5 * s / (double)B_ROWS - 0.5 * (double)N_COLS);
    }
}

extern "C" void kernel_launch(void* const* d_in, const int* in_sizes, int n_in,
                              void* d_out, int out_size, void* d_ws, size_t ws_size,
                              hipStream_t stream) {
    const float4* mu1  = (const float4*)d_in[0];
    const float4* mu2  = (const float4*)d_in[1];
    const float4* sg1  = (const float4*)d_in[2];
    const float4* sg2  = (const float4*)d_in[3];
    const float4* mask = (const float4*)d_in[4];
    float* partials = (float*)d_ws;  // GRID1 floats = 16 KiB scratch
    float* out = (float*)d_out;

    kl_partial_kernel<<<GRID1, BLOCK, 0, stream>>>(mu1, mu2, sg1, sg2, mask, partials);
    kl_final_kernel<<<1, BLOCK, 0, stream>>>(partials, out);
}